// Round 7
// baseline (188.796 us; speedup 1.0000x reference)
//
#include <hip/hip_runtime.h>
#include <hip/hip_bf16.h>
#include <math.h>

#define F 8
#define C 4096
#define NPAIR 36            // F*(F+1)/2 pairs with i<=j
#define EPSF 1e-8f
#define QT 512              // q-chunk length; 8 * 512 * 4B = 16 KB LDS
#define NQC 8               // C / QT
#define NRG 1024            // row-groups of 4 rows (1 per wave)
#define NGB (NRG * NQC)     // 8192 G-blocks (triangle: ~44% empty, exit fast)
#define NSB 512             // row-sum blocks (8 rows each, 2 per wave)

// ws layout (floats):
//   Gpart : [NPAIR][NGB]   per-block partial G_ij over the q>p triangle
//   spart : [F][C]         full row sums s_f[p]
// Every element is written before finish_kernel reads it (empty G-blocks
// write zeros) -> no zero-init kernel, no atomics.

__device__ __forceinline__ float wave_reduce(float v) {
    #pragma unroll
    for (int off = 32; off > 0; off >>= 1) v += __shfl_down(v, off, 64);
    return v;
}

__device__ __forceinline__ float fast_sqrt(float v) {
    return __builtin_amdgcn_sqrtf(v);
}

// wave-uniform float -> SGPR
__device__ __forceinline__ float rfl(float v) {
    return __uint_as_float(__builtin_amdgcn_readfirstlane(__float_as_uint(v)));
}

// Fused kernel.
//  blocks [0, NGB):      triangle Gram blocks: rows 4 per block (1/wave),
//                        q-chunk of 512. Inner loop: 8 subs + 36 FMAs per
//                        point (abs via VOP3 modifiers), NO row sums ->
//                        hot state = g[36]+d[8]+v[8], xp in SGPRs.
//  blocks [NGB, NGB+NSB): row-sum blocks: 8 rows (2/wave), full q sweep,
//                        16 ops/point.
__global__ __launch_bounds__(256) void pair_kernel(const float* __restrict__ x,
                                                   float* __restrict__ Gpart,
                                                   float* __restrict__ spart) {
    __shared__ __align__(16) float xs[F * QT];     // 16 KB
    __shared__ float red[4][NPAIR];
    const int tid  = threadIdx.x;
    const int lane = tid & 63;
    const int wave = tid >> 6;
    const float4* xg = (const float4*)x;

    if (blockIdx.x < NGB) {
        const int rg = blockIdx.x >> 3;            // row-group
        const int qc = blockIdx.x & (NQC - 1);     // q-chunk
        const int qb = qc * QT;
        const int p  = rg * 4 + wave;              // this wave's row

        // empty: all q in chunk <= smallest p in block -> no q>p pairs
        if (qb + QT - 1 <= rg * 4) {
            if (tid < NPAIR) Gpart[tid * NGB + blockIdx.x] = 0.0f;
            return;
        }

        // stage chunk: 8 factors x 512 floats = 1024 float4, 4 per thread
        #pragma unroll
        for (int i = tid; i < F * (QT / 4); i += 256) {
            const int f  = i >> 7;                 // / (QT/4)
            const int q4 = i & (QT / 4 - 1);
            ((float4*)xs)[i] = xg[f * (C / 4) + qc * (QT / 4) + q4];
        }

        float xp[F];
        #pragma unroll
        for (int f = 0; f < F; ++f) xp[f] = rfl(x[f * C + p]);

        float g[NPAIR];
        #pragma unroll
        for (int k = 0; k < NPAIR; ++k) g[k] = 0.0f;

        __syncthreads();

        if (qb > rg * 4 + 3) {
            // pure: every q in chunk > every p in block
            #pragma unroll
            for (int qt = 0; qt < QT / 64; ++qt) { // 8 iters
                const int qi = qt * 64 + lane;
                float d[F];
                #pragma unroll
                for (int f = 0; f < F; ++f) d[f] = xp[f] - xs[f * QT + qi];
                int k = 0;
                #pragma unroll
                for (int i = 0; i < F; ++i)
                    #pragma unroll
                    for (int j = i; j < F; ++j) {
                        g[k] = __builtin_fmaf(__builtin_fabsf(d[i]),
                                              __builtin_fabsf(d[j]), g[k]);
                        ++k;
                    }
            }
        } else {
            // mixed: mask lanes with q <= p (d -> 0 contributes nothing)
            const int qlo = p - qb;                // need qt*64+lane > qlo
            #pragma unroll
            for (int qt = 0; qt < QT / 64; ++qt) {
                const int qi = qt * 64 + lane;
                const bool m = qi > qlo;
                float d[F];
                #pragma unroll
                for (int f = 0; f < F; ++f) {
                    const float diff = xp[f] - xs[f * QT + qi];
                    d[f] = m ? diff : 0.0f;
                }
                int k = 0;
                #pragma unroll
                for (int i = 0; i < F; ++i)
                    #pragma unroll
                    for (int j = i; j < F; ++j) {
                        g[k] = __builtin_fmaf(__builtin_fabsf(d[i]),
                                              __builtin_fabsf(d[j]), g[k]);
                        ++k;
                    }
            }
        }

        #pragma unroll
        for (int k = 0; k < NPAIR; ++k) g[k] = wave_reduce(g[k]);
        if (lane == 0) {
            #pragma unroll
            for (int k = 0; k < NPAIR; ++k) red[wave][k] = g[k];
        }
        __syncthreads();
        if (tid < NPAIR)
            Gpart[tid * NGB + blockIdx.x] =
                red[0][tid] + red[1][tid] + red[2][tid] + red[3][tid];
    } else {
        // ---- row-sum blocks: 8 rows, 2 per wave, full q sweep ----
        const int rb = blockIdx.x - NGB;           // 0..511
        const int p0 = rb * 8 + wave * 2;

        float xp0[F], xp1[F];
        #pragma unroll
        for (int f = 0; f < F; ++f) {
            xp0[f] = rfl(x[f * C + p0]);
            xp1[f] = rfl(x[f * C + p0 + 1]);
        }
        float rs0[F], rs1[F];
        #pragma unroll
        for (int f = 0; f < F; ++f) { rs0[f] = 0.0f; rs1[f] = 0.0f; }

        for (int t = 0; t < NQC; ++t) {            // 8 tiles
            __syncthreads();
            #pragma unroll
            for (int i = tid; i < F * (QT / 4); i += 256) {
                const int f  = i >> 7;
                const int q4 = i & (QT / 4 - 1);
                ((float4*)xs)[i] = xg[f * (C / 4) + t * (QT / 4) + q4];
            }
            __syncthreads();
            #pragma unroll
            for (int qt = 0; qt < QT / 64; ++qt) {
                const int qi = qt * 64 + lane;
                #pragma unroll
                for (int f = 0; f < F; ++f) {
                    const float v = xs[f * QT + qi];
                    rs0[f] += __builtin_fabsf(xp0[f] - v);
                    rs1[f] += __builtin_fabsf(xp1[f] - v);
                }
            }
        }
        #pragma unroll
        for (int f = 0; f < F; ++f) {
            rs0[f] = wave_reduce(rs0[f]);
            rs1[f] = wave_reduce(rs1[f]);
        }
        if (lane == 0) {
            #pragma unroll
            for (int f = 0; f < F; ++f) {
                spart[f * C + p0]     = rs0[f];
                spart[f * C + p0 + 1] = rs1[f];
            }
        }
    }
}

// 1 block, 1024 threads = 16 waves.
// Phase A: D (36 dots of row sums) + T (8 totals) from spart.
// Phase B: reduce Gpart rows (float4-coalesced), x2 for the triangle.
__global__ __launch_bounds__(1024) void finish_kernel(const float* __restrict__ Gpart,
                                                      const float* __restrict__ spart,
                                                      float* __restrict__ out) {
    const int tid  = threadIdx.x;
    const int lane = tid & 63;
    const int wave = tid >> 6;      // 0..15

    __shared__ float redD[16][NPAIR];
    __shared__ float redT[16][F];
    __shared__ float Gs[NPAIR];
    __shared__ float Dt[NPAIR];
    __shared__ float Tt[F];

    float D[NPAIR], T[F];
    #pragma unroll
    for (int k = 0; k < NPAIR; ++k) D[k] = 0.0f;
    #pragma unroll
    for (int f = 0; f < F; ++f) T[f] = 0.0f;

    #pragma unroll
    for (int it = 0; it < C / 1024; ++it) {        // 4 iterations
        const int p = it * 1024 + tid;
        float sv[F];
        #pragma unroll
        for (int f = 0; f < F; ++f) { sv[f] = spart[f * C + p]; T[f] += sv[f]; }
        int k = 0;
        #pragma unroll
        for (int i = 0; i < F; ++i)
            #pragma unroll
            for (int j = i; j < F; ++j) { D[k] += sv[i] * sv[j]; ++k; }
    }
    #pragma unroll
    for (int k = 0; k < NPAIR; ++k) D[k] = wave_reduce(D[k]);
    #pragma unroll
    for (int f = 0; f < F; ++f) T[f] = wave_reduce(T[f]);
    if (lane == 0) {
        #pragma unroll
        for (int k = 0; k < NPAIR; ++k) redD[wave][k] = D[k];
        #pragma unroll
        for (int f = 0; f < F; ++f) redT[wave][f] = T[f];
    }

    // Phase B: wave w reduces G rows w, w+16, w+32 (8192 floats = 2048 float4)
    for (int k = wave; k < NPAIR; k += 16) {
        const float4* gp = (const float4*)(Gpart + k * NGB);
        float s = 0.0f;
        #pragma unroll
        for (int it = 0; it < NGB / 256; ++it) {   // 32 float4 per lane
            const float4 v = gp[it * 64 + lane];
            s += (v.x + v.y) + (v.z + v.w);
        }
        s = wave_reduce(s);
        if (lane == 0) Gs[k] = s;
    }
    __syncthreads();

    if (tid < NPAIR) {
        float s = 0.0f;
        #pragma unroll
        for (int w = 0; w < 16; ++w) s += redD[w][tid];
        Dt[tid] = s;
    } else if (tid >= 64 && tid < 64 + F) {
        const int f = tid - 64;
        float s = 0.0f;
        #pragma unroll
        for (int w = 0; w < 16; ++w) s += redT[w][f];
        Tt[f] = s;
    }
    __syncthreads();

    if (tid == 0) {
        const float invC  = 1.0f / (float)C;        // 2^-12, exact
        const float invC2 = invC * invC;            // 2^-24, exact
        float dcov[NPAIR], diag[F];
        int k = 0;
        for (int i = 0; i < F; ++i)
            for (int j = i; j < F; ++j) {
                // G_full = 2 * G_triangle (a[p][q] symmetric, diag 0)
                float S = 2.0f * Gs[k] * invC2 - 2.0f * Dt[k] * invC2 * invC +
                          (Tt[i] * invC2) * (Tt[j] * invC2);
                float dc = fast_sqrt(fmaxf(S, 0.0f) + EPSF);
                dcov[k] = dc;
                if (i == j) diag[i] = dc;
                ++k;
            }
        float cor = 0.0f;
        k = 0;
        for (int i = 0; i < F; ++i)
            for (int j = i; j < F; ++j) {
                if (j > i) cor += dcov[k] * __builtin_amdgcn_rcpf(
                                      fast_sqrt(diag[i] * diag[j] + EPSF));
                ++k;
            }
        out[0] = cor;
    }
}

extern "C" void kernel_launch(void* const* d_in, const int* in_sizes, int n_in,
                              void* d_out, int out_size, void* d_ws, size_t ws_size,
                              hipStream_t stream) {
    const float* x = (const float*)d_in[0];
    float* Gpart = (float*)d_ws;                 // [36][8192]
    float* spart = Gpart + NPAIR * NGB;          // [8][4096]
    float* out   = (float*)d_out;

    hipLaunchKernelGGL(pair_kernel,   dim3(NGB + NSB), dim3(256),  0, stream,
                       x, Gpart, spart);
    hipLaunchKernelGGL(finish_kernel, dim3(1),         dim3(1024), 0, stream,
                       Gpart, spart, out);
}

// Round 8
// 129.946 us; speedup vs baseline: 1.4529x; 1.4529x over previous
//
#include <hip/hip_runtime.h>
#include <hip/hip_bf16.h>
#include <math.h>

#define F 8
#define C 4096
#define NPAIR 36            // F*(F+1)/2 pairs with i<=j
#define EPSF 1e-8f
#define NGB 1024            // G-blocks: 512 row-groups x 2 iteration parities
#define NRSB 256            // row-sum blocks: 16 rows each (4 per wave)
#define QT 1024             // LDS tile; 8 * 1024 * 4B = 32 KB
#define NIT 16              // 256-point iterations over C

// ws layout (floats):
//   Gpart : [NPAIR][NGB]   per-block partial G_ij over the q>p triangle
//   spart : [F][C]         full row sums s_f[p]
// Everything is written before finish_kernel reads it -> no zero-init,
// no atomics.

__device__ __forceinline__ float wave_reduce(float v) {
    #pragma unroll
    for (int off = 32; off > 0; off >>= 1) v += __shfl_down(v, off, 64);
    return v;
}

__device__ __forceinline__ float fast_sqrt(float v) {
    return __builtin_amdgcn_sqrtf(v);
}

// wave-uniform float -> SGPR
__device__ __forceinline__ float rfl(float v) {
    return __uint_as_float(__builtin_amdgcn_readfirstlane(__float_as_uint(v)));
}

// 4 q-points (one float4 per factor) for one row, interior (all q > p).
__device__ __forceinline__ void pt4(const float4 v[F], const float xp[F],
                                    float g[NPAIR]) {
    float d0[F], d1[F], d2[F], d3[F];
    #pragma unroll
    for (int f = 0; f < F; ++f) {
        d0[f] = xp[f] - v[f].x;
        d1[f] = xp[f] - v[f].y;
        d2[f] = xp[f] - v[f].z;
        d3[f] = xp[f] - v[f].w;
    }
    int k = 0;
    #pragma unroll
    for (int i = 0; i < F; ++i)
        #pragma unroll
        for (int j = i; j < F; ++j) {
            g[k] = __builtin_fmaf(__builtin_fabsf(d0[i]), __builtin_fabsf(d0[j]), g[k]);
            g[k] = __builtin_fmaf(__builtin_fabsf(d1[i]), __builtin_fabsf(d1[j]), g[k]);
            g[k] = __builtin_fmaf(__builtin_fabsf(d2[i]), __builtin_fabsf(d2[j]), g[k]);
            g[k] = __builtin_fmaf(__builtin_fabsf(d3[i]), __builtin_fabsf(d3[j]), g[k]);
            ++k;
        }
}

// Boundary variant: zero components with q <= p. qg0 = global q of comp .x.
__device__ __forceinline__ void pt4_mask(const float4 v[F], const float xp[F],
                                         float g[NPAIR], int qg0, int p) {
    const bool m0 = qg0     > p;
    const bool m1 = qg0 + 1 > p;
    const bool m2 = qg0 + 2 > p;
    const bool m3 = qg0 + 3 > p;
    float d0[F], d1[F], d2[F], d3[F];
    #pragma unroll
    for (int f = 0; f < F; ++f) {
        d0[f] = m0 ? (xp[f] - v[f].x) : 0.0f;
        d1[f] = m1 ? (xp[f] - v[f].y) : 0.0f;
        d2[f] = m2 ? (xp[f] - v[f].z) : 0.0f;
        d3[f] = m3 ? (xp[f] - v[f].w) : 0.0f;
    }
    int k = 0;
    #pragma unroll
    for (int i = 0; i < F; ++i)
        #pragma unroll
        for (int j = i; j < F; ++j) {
            g[k] = __builtin_fmaf(__builtin_fabsf(d0[i]), __builtin_fabsf(d0[j]), g[k]);
            g[k] = __builtin_fmaf(__builtin_fabsf(d1[i]), __builtin_fabsf(d1[j]), g[k]);
            g[k] = __builtin_fmaf(__builtin_fabsf(d2[i]), __builtin_fabsf(d2[j]), g[k]);
            g[k] = __builtin_fmaf(__builtin_fabsf(d3[i]), __builtin_fabsf(d3[j]), g[k]);
            ++k;
        }
}

// Blocks [0,NGB): triangle Gram. Each wave owns the complementary row pair
// (pA, 4095-pA) -> spans sum to 4096 points (balanced). Blocks come in
// parity pairs: block handles iterations g with (g&1)==parity (256 q each),
// so per-wave work ~2048 points with full-sweep amortization of the final
// wave_reduce. Blocks [NGB, NGB+NRSB): row sums, 4 rows/wave, full sweep.
__global__ __launch_bounds__(256) void pair_kernel(const float* __restrict__ x,
                                                   float* __restrict__ Gpart,
                                                   float* __restrict__ spart) {
    __shared__ __align__(16) float xs[F * QT];     // 32 KB
    __shared__ float red[4][NPAIR];
    const int tid  = threadIdx.x;
    const int lane = tid & 63;
    const int wave = __builtin_amdgcn_readfirstlane(tid >> 6);
    const float4* xg = (const float4*)x;

    if (blockIdx.x < NGB) {
        const int rg  = blockIdx.x >> 1;           // row-group 0..511
        const int par = blockIdx.x & 1;            // iteration parity
        const int pA  = rg * 4 + wave;             // 0..2047
        const int pB  = (C - 1) - pA;              // 2048..4095
        const int aF  = pA >> 8;                   // first active iter, row A
        const int bF  = pB >> 8;                   // first active iter, row B

        float xpA[F], xpB[F];
        #pragma unroll
        for (int f = 0; f < F; ++f) {
            xpA[f] = rfl(x[f * C + pA]);
            xpB[f] = rfl(x[f * C + pB]);
        }

        float g[NPAIR];
        #pragma unroll
        for (int k = 0; k < NPAIR; ++k) g[k] = 0.0f;

        for (int t = 0; t < 4; ++t) {              // 4 LDS tiles of 1024
            __syncthreads();
            // block-uniform tile skip: no iter in this tile is active for
            // any wave (min aF over block = (rg*4)>>8, min bF = (4092-rg*4)>>8)
            const int gHi = t * 4 + 3;
            const bool tileLive = (gHi >= ((rg * 4) >> 8)) ||
                                  (gHi >= ((C - 4 - rg * 4) >> 8));
            if (tileLive) {
                #pragma unroll
                for (int i = tid; i < F * (QT / 4); i += 256) {
                    const int f  = i >> 8;         // / (QT/4)
                    const int q4 = i & (QT / 4 - 1);
                    ((float4*)xs)[i] = xg[f * (C / 4) + t * (QT / 4) + q4];
                }
            }
            __syncthreads();
            if (!tileLive) continue;

            #pragma unroll
            for (int qt = 0; qt < 4; ++qt) {
                const int gIt = t * 4 + qt;        // global iteration 0..15
                if ((gIt & 1) != par) continue;    // uniform
                const bool aAct = gIt >= aF;
                const bool bAct = gIt >= bF;
                if (!aAct && !bAct) continue;      // uniform

                const int qi = qt * 64 + lane;     // float4 index in tile
                float4 v[F];
                #pragma unroll
                for (int f = 0; f < F; ++f)
                    v[f] = ((const float4*)xs)[f * (QT / 4) + qi];

                const int qg0 = t * QT + qi * 4;   // global q of comp .x
                if (aAct) {
                    if (gIt == aF) pt4_mask(v, xpA, g, qg0, pA);
                    else           pt4(v, xpA, g);
                }
                if (bAct) {
                    if (gIt == bF) pt4_mask(v, xpB, g, qg0, pB);
                    else           pt4(v, xpB, g);
                }
            }
        }

        #pragma unroll
        for (int k = 0; k < NPAIR; ++k) g[k] = wave_reduce(g[k]);
        if (lane == 0) {
            #pragma unroll
            for (int k = 0; k < NPAIR; ++k) red[wave][k] = g[k];
        }
        __syncthreads();
        if (tid < NPAIR)
            Gpart[tid * NGB + blockIdx.x] =
                red[0][tid] + red[1][tid] + red[2][tid] + red[3][tid];
    } else {
        // ---- row-sum blocks: 16 rows, 4 per wave, full q sweep ----
        const int rb = blockIdx.x - NGB;           // 0..255
        const int p0 = rb * 16 + wave * 4;

        float xp[4][F];
        #pragma unroll
        for (int r = 0; r < 4; ++r)
            #pragma unroll
            for (int f = 0; f < F; ++f) xp[r][f] = rfl(x[f * C + p0 + r]);

        float rs[4][F];
        #pragma unroll
        for (int r = 0; r < 4; ++r)
            #pragma unroll
            for (int f = 0; f < F; ++f) rs[r][f] = 0.0f;

        for (int t = 0; t < 4; ++t) {
            __syncthreads();
            #pragma unroll
            for (int i = tid; i < F * (QT / 4); i += 256) {
                const int f  = i >> 8;
                const int q4 = i & (QT / 4 - 1);
                ((float4*)xs)[i] = xg[f * (C / 4) + t * (QT / 4) + q4];
            }
            __syncthreads();
            #pragma unroll
            for (int qt = 0; qt < 4; ++qt) {
                const int qi = qt * 64 + lane;
                float4 v[F];
                #pragma unroll
                for (int f = 0; f < F; ++f)
                    v[f] = ((const float4*)xs)[f * (QT / 4) + qi];
                #pragma unroll
                for (int r = 0; r < 4; ++r)
                    #pragma unroll
                    for (int f = 0; f < F; ++f) {
                        rs[r][f] += __builtin_fabsf(xp[r][f] - v[f].x) +
                                    __builtin_fabsf(xp[r][f] - v[f].y);
                        rs[r][f] += __builtin_fabsf(xp[r][f] - v[f].z) +
                                    __builtin_fabsf(xp[r][f] - v[f].w);
                    }
            }
        }
        #pragma unroll
        for (int r = 0; r < 4; ++r)
            #pragma unroll
            for (int f = 0; f < F; ++f) rs[r][f] = wave_reduce(rs[r][f]);
        if (lane == 0) {
            #pragma unroll
            for (int r = 0; r < 4; ++r)
                #pragma unroll
                for (int f = 0; f < F; ++f) spart[f * C + p0 + r] = rs[r][f];
        }
    }
}

// 1 block, 1024 threads = 16 waves.
// Phase A: D (36 dots of row sums) + T (8 totals) from spart.
// Phase B: reduce Gpart rows (float4), x2 in epilogue for the triangle.
__global__ __launch_bounds__(1024) void finish_kernel(const float* __restrict__ Gpart,
                                                      const float* __restrict__ spart,
                                                      float* __restrict__ out) {
    const int tid  = threadIdx.x;
    const int lane = tid & 63;
    const int wave = tid >> 6;      // 0..15

    __shared__ float redD[16][NPAIR];
    __shared__ float redT[16][F];
    __shared__ float Gs[NPAIR];
    __shared__ float Dt[NPAIR];
    __shared__ float Tt[F];

    float D[NPAIR], T[F];
    #pragma unroll
    for (int k = 0; k < NPAIR; ++k) D[k] = 0.0f;
    #pragma unroll
    for (int f = 0; f < F; ++f) T[f] = 0.0f;

    #pragma unroll
    for (int it = 0; it < C / 1024; ++it) {        // 4 iterations
        const int p = it * 1024 + tid;
        float sv[F];
        #pragma unroll
        for (int f = 0; f < F; ++f) { sv[f] = spart[f * C + p]; T[f] += sv[f]; }
        int k = 0;
        #pragma unroll
        for (int i = 0; i < F; ++i)
            #pragma unroll
            for (int j = i; j < F; ++j) { D[k] += sv[i] * sv[j]; ++k; }
    }
    #pragma unroll
    for (int k = 0; k < NPAIR; ++k) D[k] = wave_reduce(D[k]);
    #pragma unroll
    for (int f = 0; f < F; ++f) T[f] = wave_reduce(T[f]);
    if (lane == 0) {
        #pragma unroll
        for (int k = 0; k < NPAIR; ++k) redD[wave][k] = D[k];
        #pragma unroll
        for (int f = 0; f < F; ++f) redT[wave][f] = T[f];
    }

    // Phase B: wave w reduces G rows w, w+16, w+32 (1024 floats = 256 float4)
    for (int k = wave; k < NPAIR; k += 16) {
        const float4* gp = (const float4*)(Gpart + k * NGB);
        float s = 0.0f;
        #pragma unroll
        for (int it = 0; it < NGB / 256; ++it) {   // 4 float4 per lane
            const float4 v = gp[it * 64 + lane];
            s += (v.x + v.y) + (v.z + v.w);
        }
        s = wave_reduce(s);
        if (lane == 0) Gs[k] = s;
    }
    __syncthreads();

    if (tid < NPAIR) {
        float s = 0.0f;
        #pragma unroll
        for (int w = 0; w < 16; ++w) s += redD[w][tid];
        Dt[tid] = s;
    } else if (tid >= 64 && tid < 64 + F) {
        const int f = tid - 64;
        float s = 0.0f;
        #pragma unroll
        for (int w = 0; w < 16; ++w) s += redT[w][f];
        Tt[f] = s;
    }
    __syncthreads();

    if (tid == 0) {
        const float invC  = 1.0f / (float)C;        // 2^-12, exact
        const float invC2 = invC * invC;            // 2^-24, exact
        float dcov[NPAIR], diag[F];
        int k = 0;
        for (int i = 0; i < F; ++i)
            for (int j = i; j < F; ++j) {
                // G_full = 2 * G_triangle (a symmetric, zero diagonal)
                float S = 2.0f * Gs[k] * invC2 - 2.0f * Dt[k] * invC2 * invC +
                          (Tt[i] * invC2) * (Tt[j] * invC2);
                float dc = fast_sqrt(fmaxf(S, 0.0f) + EPSF);
                dcov[k] = dc;
                if (i == j) diag[i] = dc;
                ++k;
            }
        float cor = 0.0f;
        k = 0;
        for (int i = 0; i < F; ++i)
            for (int j = i; j < F; ++j) {
                if (j > i) cor += dcov[k] * __builtin_amdgcn_rcpf(
                                      fast_sqrt(diag[i] * diag[j] + EPSF));
                ++k;
            }
        out[0] = cor;
    }
}

extern "C" void kernel_launch(void* const* d_in, const int* in_sizes, int n_in,
                              void* d_out, int out_size, void* d_ws, size_t ws_size,
                              hipStream_t stream) {
    const float* x = (const float*)d_in[0];
    float* Gpart = (float*)d_ws;                 // [36][1024]
    float* spart = Gpart + NPAIR * NGB;          // [8][4096]
    float* out   = (float*)d_out;

    hipLaunchKernelGGL(pair_kernel,   dim3(NGB + NRSB), dim3(256),  0, stream,
                       x, Gpart, spart);
    hipLaunchKernelGGL(finish_kernel, dim3(1),          dim3(1024), 0, stream,
                       Gpart, spart, out);
}